// Round 10
// baseline (110.709 us; speedup 1.0000x reference)
//
#include <hip/hip_runtime.h>
#include <hip/hip_fp16.h>

#define N_NODES 20000
#define N_EDGES 320000
#define E_TOT   (N_EDGES + N_NODES)     // self-loops appended virtually
#define D       128
#define D_OUT   8
#define MAXDEG  64
#define NTILE   (N_NODES / 16)          // 1250
#define MLP_BLOCKS 313
#define BUCKET_BLOCKS ((E_TOT + 255) / 256)   // 1329

typedef _Float16 f16x8 __attribute__((ext_vector_type(8)));
typedef float    f32x4 __attribute__((ext_vector_type(4)));

__device__ __forceinline__ void split8(const float* v, f16x8& hi, f16x8& lo) {
#pragma unroll
    for (int e = 0; e < 8; ++e) {
        _Float16 h = (_Float16)v[e];
        hi[e] = h; lo[e] = (_Float16)(v[e] - (float)h);
    }
}

// ================= prep: zero cnt + all weight transposes =================
__global__ void prep_kernel(const float* __restrict__ W1, const float* __restrict__ W2,
                            const float* __restrict__ Wt0, const float* __restrict__ Ws0,
                            const float* __restrict__ Wh0, const float* __restrict__ Wt1,
                            const float* __restrict__ Ws1, const float* __restrict__ Wh1,
                            __half* __restrict__ W1c, __half* __restrict__ W2c,
                            __half* __restrict__ Wc2, int* __restrict__ cnt) {
    const int b = blockIdx.x, tid = threadIdx.x;
    if (b < 79) {
        int i = b * 256 + tid;
        if (i < N_NODES) cnt[i] = 0;
        return;
    }
    if (b < 143) {
        int idx = (b - 79) * 256 + tid;        // 0..16383
        if (idx < 4096) {
            int c = idx >> 5, k = idx & 31;
            W1c[c * 32 + k] = __float2half(W1[k * D + c]);
        }
        int c = idx >> 7, k = idx & 127;
        W2c[c * 128 + k] = __float2half(W2[k * D + c]);
        return;
    }
    int bb = b - 143;                          // 0..383
    int l = bb / 192, r = bb % 192, m = r / 64, kp = r % 64;
    int k = kp * 2 + (tid >> 7), c = tid & 127;
    const float* W = (l == 0) ? (m == 0 ? Wt0 : m == 1 ? Ws0 : Wh0)
                              : (m == 0 ? Wt1 : m == 1 ? Ws1 : Wh1);
    Wc2[l * 49152 + (m * 128 + c) * 128 + k] = __float2half(W[(size_t)k * D + c]);
}

// ========== build_fwd: fused mlp1->mlp2->proj3(l0) (blocks 0..312) + bucket scatter ==========
__global__ __launch_bounds__(256) void build_fwd(
        const int* __restrict__ ei, int* __restrict__ cnt, int* __restrict__ slots,
        const float* __restrict__ x,
        const __half* __restrict__ W1c, const __half* __restrict__ W2c,
        const float* __restrict__ b1, const float* __restrict__ b2,
        const __half* __restrict__ Wc0,
        const float* __restrict__ bt, const float* __restrict__ bs,
        const float* __restrict__ bh,
        float* __restrict__ pt0, __half* __restrict__ psn0) {
    if (blockIdx.x >= MLP_BLOCKS) {            // ---- bucket scatter blocks ----
        int e = (blockIdx.x - MLP_BLOCKS) * 256 + threadIdx.x;
        if (e < E_TOT) {
            int src, dst;
            if (e < N_EDGES) { src = ei[e]; dst = ei[N_EDGES + e]; }
            else             { src = dst = e - N_EDGES; }
            int pos = atomicAdd(&cnt[dst], 1);
            if (pos < MAXDEG) slots[dst * MAXDEG + pos] = src;
        }
        return;
    }
    // ---- fused MLP + layer-0 projection; h tiles live in LDS as f16 hi/lo ----
    __shared__ __half hHi[4][16][136];   // 17 KB
    __shared__ __half hLo[4][16][136];   // 17 KB
    const int tb   = blockIdx.x;                   // 0..312
    const int tid  = threadIdx.x;
    const int lane = tid & 63, wv = tid >> 6;
    const int cl   = lane & 15, kg = (lane >> 4) * 8;
    const int rj   = (lane >> 4) * 4;
    const int tg   = min(tb * 4 + wv, NTILE - 1);

    // ---- stage 1: h1 = relu(x @ W1 + b1) ----
    {
        const int row = tg * 16 + cl;
        float tmp[8];
        *(float4*)tmp       = *(const float4*)(x + (size_t)row * 32 + kg);
        *(float4*)(tmp + 4) = *(const float4*)(x + (size_t)row * 32 + kg + 4);
        f16x8 aH, aL; split8(tmp, aH, aL);
        f32x4 acc[8];
#pragma unroll
        for (int ct = 0; ct < 8; ++ct) acc[ct] = (f32x4){0.f, 0.f, 0.f, 0.f};
#pragma unroll
        for (int ct = 0; ct < 8; ++ct) {
            const f16x8 bf = *(const f16x8*)(W1c + (size_t)(ct * 16 + cl) * 32 + kg);
            acc[ct] = __builtin_amdgcn_mfma_f32_16x16x32_f16(aH, bf, acc[ct], 0, 0, 0);
            acc[ct] = __builtin_amdgcn_mfma_f32_16x16x32_f16(aL, bf, acc[ct], 0, 0, 0);
        }
#pragma unroll
        for (int ct = 0; ct < 8; ++ct) {
            const float bb = b1[ct * 16 + cl];
#pragma unroll
            for (int j = 0; j < 4; ++j) {
                float v = fmaxf(acc[ct][j] + bb, 0.f);
                _Float16 h = (_Float16)v;
                ((_Float16*)&hHi[wv][rj + j][ct * 16 + cl])[0] = h;
                ((_Float16*)&hLo[wv][rj + j][ct * 16 + cl])[0] = (_Float16)(v - (float)h);
            }
        }
    }
    __syncthreads();
    // ---- stage 2: h = relu(h1 @ W2 + b2) ----
    {
        f16x8 aH[4], aL[4];
#pragma unroll
        for (int ks = 0; ks < 4; ++ks) {
            aH[ks] = *(const f16x8*)&hHi[wv][cl][ks * 32 + kg];
            aL[ks] = *(const f16x8*)&hLo[wv][cl][ks * 32 + kg];
        }
        f32x4 acc[8];
#pragma unroll
        for (int ct = 0; ct < 8; ++ct) acc[ct] = (f32x4){0.f, 0.f, 0.f, 0.f};
#pragma unroll
        for (int ks = 0; ks < 4; ++ks)
#pragma unroll
            for (int ct = 0; ct < 8; ++ct) {
                const f16x8 bf = *(const f16x8*)(W2c + (size_t)(ct * 16 + cl) * 128 + ks * 32 + kg);
                acc[ct] = __builtin_amdgcn_mfma_f32_16x16x32_f16(aH[ks], bf, acc[ct], 0, 0, 0);
                acc[ct] = __builtin_amdgcn_mfma_f32_16x16x32_f16(aL[ks], bf, acc[ct], 0, 0, 0);
            }
        __syncthreads();
#pragma unroll
        for (int ct = 0; ct < 8; ++ct) {
            const float bb = b2[ct * 16 + cl];
#pragma unroll
            for (int j = 0; j < 4; ++j) {
                float v = fmaxf(acc[ct][j] + bb, 0.f);
                _Float16 h = (_Float16)v;
                ((_Float16*)&hHi[wv][rj + j][ct * 16 + cl])[0] = h;
                ((_Float16*)&hLo[wv][rj + j][ct * 16 + cl])[0] = (_Float16)(v - (float)h);
            }
        }
    }
    __syncthreads();
    // ---- stage 3: proj3 layer0 ----
    const int ctl[6] = {2 * wv, 2 * wv + 1, 8 + 2 * wv, 9 + 2 * wv, 16 + 2 * wv, 17 + 2 * wv};
    f16x8 bf[6][4];
#pragma unroll
    for (int i = 0; i < 6; ++i)
#pragma unroll
        for (int ks = 0; ks < 4; ++ks)
            bf[i][ks] = *(const f16x8*)(Wc0 + (size_t)(ctl[i] * 16 + cl) * 128 + ks * 32 + kg);

    __half2* psn2 = (__half2*)psn0;
    for (int rt = 0; rt < 4; ++rt) {
        const int tg2 = min(tb * 4 + rt, NTILE - 1);
        f16x8 aH[4], aL[4];
#pragma unroll
        for (int ks = 0; ks < 4; ++ks) {
            aH[ks] = *(const f16x8*)&hHi[rt][cl][ks * 32 + kg];
            aL[ks] = *(const f16x8*)&hLo[rt][cl][ks * 32 + kg];
        }
        f32x4 acc[6];
#pragma unroll
        for (int i = 0; i < 6; ++i) acc[i] = (f32x4){0.f, 0.f, 0.f, 0.f};
#pragma unroll
        for (int i = 0; i < 6; ++i)
#pragma unroll
            for (int ks = 0; ks < 4; ++ks) {
                acc[i] = __builtin_amdgcn_mfma_f32_16x16x32_f16(aH[ks], bf[i][ks], acc[i], 0, 0, 0);
                acc[i] = __builtin_amdgcn_mfma_f32_16x16x32_f16(aL[ks], bf[i][ks], acc[i], 0, 0, 0);
            }
        const int rbase = tg2 * 16 + rj;
#pragma unroll
        for (int i = 0; i < 2; ++i) {
            const int c = ctl[i] * 16 + cl;
            const float bb = bt[c];
#pragma unroll
            for (int j = 0; j < 4; ++j)
                pt0[(size_t)(rbase + j) * D + c] = fmaxf(acc[i][j] + bb, 0.f);
        }
#pragma unroll
        for (int p = 0; p < 2; ++p) {
            const int c = (ctl[2 + p] - 8) * 16 + cl;
            const float bS = bs[c], bN = bh[c];
#pragma unroll
            for (int j = 0; j < 4; ++j) {
                float vS = fmaxf(acc[2 + p][j] + bS, 0.f);
                float vN = fmaxf(acc[4 + p][j] + bN, 0.f);
                psn2[(size_t)(rbase + j) * 128 + c] = __floats2half2_rn(vS, vN);
            }
        }
    }
}

// ================= gather core: one node per 32-lane half-wave, TWO HEAD-PASSES =================
// psn pair layout: psn[2c]=ps[c], psn[2c+1]=pn[c].
// Pass P handles cols 64P..64P+63 (heads 4P..4P+3): lane owns cols 64P+2*l32, +1
// -> uint2 at half-offset 128P + 4*l32. Working set per pass = 5.1 MB (vs 10.2).
#define LDV(kk) (*(const uint2*)(psn + (size_t)__shfl(sv, hbase + (kk)) * 256 + poff + 4 * l32))

#define PROC(v, kk) {                                                     \
    const float2 p0 = __half22float2(__builtin_bit_cast(__half2, (v).x)); \
    const float2 p1 = __half22float2(__builtin_bit_cast(__half2, (v).y)); \
    float d_ = ptv.x * p0.x + ptv.y * p1.x;                               \
    d_ += __shfl_xor(d_, 1);                                              \
    d_ += __shfl_xor(d_, 2);                                              \
    d_ += __shfl_xor(d_, 4);                                              \
    const float ex_ = (base + (kk) < len) ? __expf(d_) : 0.f;             \
    sA += ex_; M0 += ex_ * p0.y; M1 += ex_ * p1.y; }

__device__ __forceinline__ void gat_node(
        const float* __restrict__ pt, const __half* __restrict__ psn,
        const int* __restrict__ cnt, const int* __restrict__ slots,
        const float* __restrict__ Wo, const float* __restrict__ bo,
        int node, int l32, int hbase, float hv[4]) {
    const int len = min(cnt[node], MAXDEG);          // >= 1 (self-loop)
    const int maxlen = max(len, __shfl_xor(len, 32));
    const int e0 = node * MAXDEG;

    float avc[2];                                    // combined over both passes
    avc[0] = 0.f; avc[1] = 0.f;
#pragma unroll
    for (int pass = 0; pass < 2; ++pass) {
        const int poff = pass * 128;
        const float2 ptv = *(const float2*)(pt + (size_t)node * D + pass * 64 + 2 * l32);
        float sA = 0.f, M0 = 0.f, M1 = 0.f;
        for (int base = 0; base < maxlen; base += 32) {
            const int sv = slots[e0 + min(base + l32, len - 1)];
            const int kmax = min(32, maxlen - base);
            uint2 va = LDV(0);
            uint2 vb = LDV(min(1, kmax - 1));
            uint2 vc = LDV(min(2, kmax - 1));
            uint2 vd = LDV(min(3, kmax - 1));
            for (int k = 0; k < kmax; k += 4) {
                const int kn = k + 4;
                uint2 wa = LDV(min(kn,     kmax - 1));
                uint2 wb = LDV(min(kn + 1, kmax - 1));
                uint2 wc = LDV(min(kn + 2, kmax - 1));
                uint2 wd = LDV(min(kn + 3, kmax - 1));
                PROC(va, k); PROC(vb, k + 1); PROC(vc, k + 2); PROC(vd, k + 3);
                va = wa; vb = wb; vc = wc; vd = wd;
            }
        }
        // per-head normalize (sA replicated within 8-lane head group), then
        // sum across the pass's 4 heads (lanes xor 8, 16)
        const float inv = 1.f / (sA + 1e-12f);
        float m0 = M0 * inv, m1 = M1 * inv;
        m0 += __shfl_xor(m0, 8);  m1 += __shfl_xor(m1, 8);
        m0 += __shfl_xor(m0, 16); m1 += __shfl_xor(m1, 16);
        avc[0] += m0; avc[1] += m1;
    }
    avc[0] *= 0.125f; avc[1] *= 0.125f;
    // lane l32 holds agg in-head cols 2*(l32&7), 2*(l32&7)+1 (replicated x4)

    float a0 = bo[l32], a1 = bo[l32 + 32], a2 = bo[l32 + 64], a3 = bo[l32 + 96];
#pragma unroll
    for (int k = 0; k < 16; ++k) {
        const float val = __shfl(avc[k & 1], hbase + (k >> 1));
        a0 += val * Wo[k * D + l32];
        a1 += val * Wo[k * D + l32 + 32];
        a2 += val * Wo[k * D + l32 + 64];
        a3 += val * Wo[k * D + l32 + 96];
    }
    hv[0] = fmaxf(a0, 0.f); hv[1] = fmaxf(a1, 0.f);
    hv[2] = fmaxf(a2, 0.f); hv[3] = fmaxf(a3, 0.f);
}

// ============ attn0: GAT layer0 + fused proj3(layer1) -> pt1/psn1 ============
__global__ __launch_bounds__(512) void attn0_kernel(
        const float* __restrict__ pt0, const __half* __restrict__ psn0,
        const int* __restrict__ cnt, const int* __restrict__ slots,
        const float* __restrict__ Wo, const float* __restrict__ bo,
        const __half* __restrict__ Wc1,
        const float* __restrict__ bt, const float* __restrict__ bs,
        const float* __restrict__ bh,
        float* __restrict__ pt1, __half* __restrict__ psn1) {
    __shared__ float h2s[16][132];
    const int tid  = threadIdx.x;
    const int lane = tid & 63;
    const int l32  = lane & 31;
    const int hbase = lane & 32;
    const int nidx = tid >> 5;                    // 0..15
    const int node = blockIdx.x * 16 + nidx;

    float hv[4];
    gat_node(pt0, psn0, cnt, slots, Wo, bo, node, l32, hbase, hv);
    h2s[nidx][l32]      = hv[0];
    h2s[nidx][l32 + 32] = hv[1];
    h2s[nidx][l32 + 64] = hv[2];
    h2s[nidx][l32 + 96] = hv[3];

    const int w_ = tid >> 6;                      // 0..7
    const int cl = lane & 15, kg = (lane >> 4) * 8;
    f16x8 bT[4], bS[4], bN[4];
#pragma unroll
    for (int ks = 0; ks < 4; ++ks) {
        bT[ks] = *(const f16x8*)(Wc1 + (size_t)((w_)      * 16 + cl) * 128 + ks * 32 + kg);
        bS[ks] = *(const f16x8*)(Wc1 + (size_t)((8 + w_)  * 16 + cl) * 128 + ks * 32 + kg);
        bN[ks] = *(const f16x8*)(Wc1 + (size_t)((16 + w_) * 16 + cl) * 128 + ks * 32 + kg);
    }
    __syncthreads();

    f16x8 aH[4], aL[4];
#pragma unroll
    for (int ks = 0; ks < 4; ++ks) {
        float tmp[8];
        *(float4*)tmp       = *(const float4*)&h2s[cl][ks * 32 + kg];
        *(float4*)(tmp + 4) = *(const float4*)&h2s[cl][ks * 32 + kg + 4];
        split8(tmp, aH[ks], aL[ks]);
    }
    f32x4 accT = {0.f,0.f,0.f,0.f}, accS = {0.f,0.f,0.f,0.f}, accN = {0.f,0.f,0.f,0.f};
#pragma unroll
    for (int ks = 0; ks < 4; ++ks) {
        accT = __builtin_amdgcn_mfma_f32_16x16x32_f16(aH[ks], bT[ks], accT, 0, 0, 0);
        accT = __builtin_amdgcn_mfma_f32_16x16x32_f16(aL[ks], bT[ks], accT, 0, 0, 0);
        accS = __builtin_amdgcn_mfma_f32_16x16x32_f16(aH[ks], bS[ks], accS, 0, 0, 0);
        accS = __builtin_amdgcn_mfma_f32_16x16x32_f16(aL[ks], bS[ks], accS, 0, 0, 0);
        accN = __builtin_amdgcn_mfma_f32_16x16x32_f16(aH[ks], bN[ks], accN, 0, 0, 0);
        accN = __builtin_amdgcn_mfma_f32_16x16x32_f16(aL[ks], bN[ks], accN, 0, 0, 0);
    }
    const int rbase = blockIdx.x * 16 + (lane >> 4) * 4;
    const int c = w_ * 16 + cl;
    const float bbT = bt[c], bbS = bs[c], bbN = bh[c];
    __half2* psn2 = (__half2*)psn1;
#pragma unroll
    for (int j = 0; j < 4; ++j) {
        pt1[(size_t)(rbase + j) * D + c] = fmaxf(accT[j] + bbT, 0.f);
        float vS = fmaxf(accS[j] + bbS, 0.f);
        float vN = fmaxf(accN[j] + bbN, 0.f);
        psn2[(size_t)(rbase + j) * 128 + c] = __floats2half2_rn(vS, vN);
    }
}

// ============ attn1: GAT layer1 + output head -> out ============
__global__ __launch_bounds__(512) void attn1_kernel(
        const float* __restrict__ pt1, const __half* __restrict__ psn1,
        const int* __restrict__ cnt, const int* __restrict__ slots,
        const float* __restrict__ Wo, const float* __restrict__ bo,
        const float* __restrict__ Wout, const float* __restrict__ bout,
        float* __restrict__ outp) {
    const int tid  = threadIdx.x;
    const int lane = tid & 63;
    const int l32  = lane & 31;
    const int hbase = lane & 32;
    const int node = blockIdx.x * 16 + (tid >> 5);

    float hv[4];
    gat_node(pt1, psn1, cnt, slots, Wo, bo, node, l32, hbase, hv);

    float po[8];
#pragma unroll
    for (int o = 0; o < 8; ++o)
        po[o] = hv[0] * Wout[l32 * D_OUT + o] + hv[1] * Wout[(l32 + 32) * D_OUT + o]
              + hv[2] * Wout[(l32 + 64) * D_OUT + o] + hv[3] * Wout[(l32 + 96) * D_OUT + o];
#pragma unroll
    for (int m = 1; m < 32; m <<= 1) {
#pragma unroll
        for (int o = 0; o < 8; ++o) po[o] += __shfl_xor(po[o], m);
    }
    if (l32 == 0) {
#pragma unroll
        for (int o = 0; o < 8; ++o)
            outp[(size_t)node * D_OUT + o] = po[o] + bout[o];
    }
}

// ================= launch =================
extern "C" void kernel_launch(void* const* d_in, const int* in_sizes, int n_in,
                              void* d_out, int out_size, void* d_ws, size_t ws_size,
                              hipStream_t stream) {
    const float* x    = (const float*)d_in[0];
    const int*   ei   = (const int*)  d_in[1];
    const float* W1   = (const float*)d_in[2];
    const float* b1   = (const float*)d_in[3];
    const float* W2   = (const float*)d_in[4];
    const float* b2   = (const float*)d_in[5];
    const float* Wout = (const float*)d_in[6];
    const float* bout = (const float*)d_in[7];
    float* out = (float*)d_out;

    // workspace layout
    float*  pt0  = (float*)d_ws;                          // N*D f32
    float*  pt1  = pt0 + (size_t)N_NODES * D;             // N*D f32
    __half* psn0 = (__half*)(pt1 + (size_t)N_NODES * D);  // N*256 f16
    __half* psn1 = psn0 + (size_t)N_NODES * 256;          // N*256 f16
    __half* W1c  = psn1 + (size_t)N_NODES * 256;          // 128*32
    __half* W2c  = W1c + 128 * 32;                        // 128*128
    __half* Wc2  = W2c + 128 * 128;                       // 2*384*128
    int* cnt   = (int*)(Wc2 + 2 * 384 * 128);             // N
    int* slots = cnt + N_NODES;                           // N*MAXDEG

    prep_kernel<<<527, 256, 0, stream>>>(
        W1, W2,
        (const float*)d_in[8],  (const float*)d_in[10], (const float*)d_in[12],
        (const float*)d_in[16], (const float*)d_in[18], (const float*)d_in[20],
        W1c, W2c, Wc2, cnt);

    build_fwd<<<MLP_BLOCKS + BUCKET_BLOCKS, 256, 0, stream>>>(
        ei, cnt, slots, x, W1c, W2c, b1, b2,
        Wc2,
        (const float*)d_in[9], (const float*)d_in[11], (const float*)d_in[13],
        pt0, psn0);

    attn0_kernel<<<NTILE, 512, 0, stream>>>(
        pt0, psn0, cnt, slots,
        (const float*)d_in[14], (const float*)d_in[15],   // Wo0, bo0
        Wc2 + 49152,
        (const float*)d_in[17], (const float*)d_in[19], (const float*)d_in[21],
        pt1, psn1);

    attn1_kernel<<<NTILE, 512, 0, stream>>>(
        pt1, psn1, cnt, slots,
        (const float*)d_in[22], (const float*)d_in[23],   // Wo1, bo1
        Wout, bout, out);
}

// Round 11
// 96.466 us; speedup vs baseline: 1.1476x; 1.1476x over previous
//
#include <hip/hip_runtime.h>
#include <hip/hip_fp16.h>

#define N_NODES 20000
#define N_EDGES 320000
#define E_TOT   (N_EDGES + N_NODES)     // self-loops appended virtually
#define D       128
#define D_OUT   8
#define MAXDEG  64
#define NTILE   (N_NODES / 16)          // 1250
#define MLP_BLOCKS 313
#define BUCKET_BLOCKS ((E_TOT + 255) / 256)   // 1329

typedef _Float16 f16x8 __attribute__((ext_vector_type(8)));
typedef float    f32x4 __attribute__((ext_vector_type(4)));

__device__ __forceinline__ void split8(const float* v, f16x8& hi, f16x8& lo) {
#pragma unroll
    for (int e = 0; e < 8; ++e) {
        _Float16 h = (_Float16)v[e];
        hi[e] = h; lo[e] = (_Float16)(v[e] - (float)h);
    }
}

// ================= prep: zero cnt + all weight transposes =================
__global__ void prep_kernel(const float* __restrict__ W1, const float* __restrict__ W2,
                            const float* __restrict__ Wt0, const float* __restrict__ Ws0,
                            const float* __restrict__ Wh0, const float* __restrict__ Wt1,
                            const float* __restrict__ Ws1, const float* __restrict__ Wh1,
                            __half* __restrict__ W1c, __half* __restrict__ W2c,
                            __half* __restrict__ Wc2, int* __restrict__ cnt) {
    const int b = blockIdx.x, tid = threadIdx.x;
    if (b < 79) {
        int i = b * 256 + tid;
        if (i < N_NODES) cnt[i] = 0;
        return;
    }
    if (b < 143) {
        int idx = (b - 79) * 256 + tid;        // 0..16383
        if (idx < 4096) {
            int c = idx >> 5, k = idx & 31;
            W1c[c * 32 + k] = __float2half(W1[k * D + c]);
        }
        int c = idx >> 7, k = idx & 127;
        W2c[c * 128 + k] = __float2half(W2[k * D + c]);
        return;
    }
    int bb = b - 143;                          // 0..383
    int l = bb / 192, r = bb % 192, m = r / 64, kp = r % 64;
    int k = kp * 2 + (tid >> 7), c = tid & 127;
    const float* W = (l == 0) ? (m == 0 ? Wt0 : m == 1 ? Ws0 : Wh0)
                              : (m == 0 ? Wt1 : m == 1 ? Ws1 : Wh1);
    Wc2[l * 49152 + (m * 128 + c) * 128 + k] = __float2half(W[(size_t)k * D + c]);
}

// ========== build_fwd: fused mlp1->mlp2->proj3(l0) (blocks 0..312) + bucket scatter ==========
__global__ __launch_bounds__(256) void build_fwd(
        const int* __restrict__ ei, int* __restrict__ cnt, int* __restrict__ slots,
        const float* __restrict__ x,
        const __half* __restrict__ W1c, const __half* __restrict__ W2c,
        const float* __restrict__ b1, const float* __restrict__ b2,
        const __half* __restrict__ Wc0,
        const float* __restrict__ bt, const float* __restrict__ bs,
        const float* __restrict__ bh,
        float* __restrict__ pt0, __half* __restrict__ psn0) {
    if (blockIdx.x >= MLP_BLOCKS) {            // ---- bucket scatter blocks ----
        int e = (blockIdx.x - MLP_BLOCKS) * 256 + threadIdx.x;
        if (e < E_TOT) {
            int src, dst;
            if (e < N_EDGES) { src = ei[e]; dst = ei[N_EDGES + e]; }
            else             { src = dst = e - N_EDGES; }
            int pos = atomicAdd(&cnt[dst], 1);
            if (pos < MAXDEG) slots[dst * MAXDEG + pos] = src;
        }
        return;
    }
    // ---- fused MLP + layer-0 projection; h tiles live in LDS as f16 hi/lo ----
    __shared__ __half hHi[4][16][136];   // 17 KB
    __shared__ __half hLo[4][16][136];   // 17 KB
    const int tb   = blockIdx.x;                   // 0..312
    const int tid  = threadIdx.x;
    const int lane = tid & 63, wv = tid >> 6;
    const int cl   = lane & 15, kg = (lane >> 4) * 8;
    const int rj   = (lane >> 4) * 4;
    const int tg   = min(tb * 4 + wv, NTILE - 1);

    // ---- stage 1: h1 = relu(x @ W1 + b1) ----
    {
        const int row = tg * 16 + cl;
        float tmp[8];
        *(float4*)tmp       = *(const float4*)(x + (size_t)row * 32 + kg);
        *(float4*)(tmp + 4) = *(const float4*)(x + (size_t)row * 32 + kg + 4);
        f16x8 aH, aL; split8(tmp, aH, aL);
        f32x4 acc[8];
#pragma unroll
        for (int ct = 0; ct < 8; ++ct) acc[ct] = (f32x4){0.f, 0.f, 0.f, 0.f};
#pragma unroll
        for (int ct = 0; ct < 8; ++ct) {
            const f16x8 bf = *(const f16x8*)(W1c + (size_t)(ct * 16 + cl) * 32 + kg);
            acc[ct] = __builtin_amdgcn_mfma_f32_16x16x32_f16(aH, bf, acc[ct], 0, 0, 0);
            acc[ct] = __builtin_amdgcn_mfma_f32_16x16x32_f16(aL, bf, acc[ct], 0, 0, 0);
        }
#pragma unroll
        for (int ct = 0; ct < 8; ++ct) {
            const float bb = b1[ct * 16 + cl];
#pragma unroll
            for (int j = 0; j < 4; ++j) {
                float v = fmaxf(acc[ct][j] + bb, 0.f);
                _Float16 h = (_Float16)v;
                ((_Float16*)&hHi[wv][rj + j][ct * 16 + cl])[0] = h;
                ((_Float16*)&hLo[wv][rj + j][ct * 16 + cl])[0] = (_Float16)(v - (float)h);
            }
        }
    }
    __syncthreads();
    // ---- stage 2: h = relu(h1 @ W2 + b2) ----
    {
        f16x8 aH[4], aL[4];
#pragma unroll
        for (int ks = 0; ks < 4; ++ks) {
            aH[ks] = *(const f16x8*)&hHi[wv][cl][ks * 32 + kg];
            aL[ks] = *(const f16x8*)&hLo[wv][cl][ks * 32 + kg];
        }
        f32x4 acc[8];
#pragma unroll
        for (int ct = 0; ct < 8; ++ct) acc[ct] = (f32x4){0.f, 0.f, 0.f, 0.f};
#pragma unroll
        for (int ks = 0; ks < 4; ++ks)
#pragma unroll
            for (int ct = 0; ct < 8; ++ct) {
                const f16x8 bf = *(const f16x8*)(W2c + (size_t)(ct * 16 + cl) * 128 + ks * 32 + kg);
                acc[ct] = __builtin_amdgcn_mfma_f32_16x16x32_f16(aH[ks], bf, acc[ct], 0, 0, 0);
                acc[ct] = __builtin_amdgcn_mfma_f32_16x16x32_f16(aL[ks], bf, acc[ct], 0, 0, 0);
            }
        __syncthreads();
#pragma unroll
        for (int ct = 0; ct < 8; ++ct) {
            const float bb = b2[ct * 16 + cl];
#pragma unroll
            for (int j = 0; j < 4; ++j) {
                float v = fmaxf(acc[ct][j] + bb, 0.f);
                _Float16 h = (_Float16)v;
                ((_Float16*)&hHi[wv][rj + j][ct * 16 + cl])[0] = h;
                ((_Float16*)&hLo[wv][rj + j][ct * 16 + cl])[0] = (_Float16)(v - (float)h);
            }
        }
    }
    __syncthreads();
    // ---- stage 3: proj3 layer0 ----
    const int ctl[6] = {2 * wv, 2 * wv + 1, 8 + 2 * wv, 9 + 2 * wv, 16 + 2 * wv, 17 + 2 * wv};
    f16x8 bf[6][4];
#pragma unroll
    for (int i = 0; i < 6; ++i)
#pragma unroll
        for (int ks = 0; ks < 4; ++ks)
            bf[i][ks] = *(const f16x8*)(Wc0 + (size_t)(ctl[i] * 16 + cl) * 128 + ks * 32 + kg);

    __half2* psn2 = (__half2*)psn0;
    for (int rt = 0; rt < 4; ++rt) {
        const int tg2 = min(tb * 4 + rt, NTILE - 1);
        f16x8 aH[4], aL[4];
#pragma unroll
        for (int ks = 0; ks < 4; ++ks) {
            aH[ks] = *(const f16x8*)&hHi[rt][cl][ks * 32 + kg];
            aL[ks] = *(const f16x8*)&hLo[rt][cl][ks * 32 + kg];
        }
        f32x4 acc[6];
#pragma unroll
        for (int i = 0; i < 6; ++i) acc[i] = (f32x4){0.f, 0.f, 0.f, 0.f};
#pragma unroll
        for (int i = 0; i < 6; ++i)
#pragma unroll
            for (int ks = 0; ks < 4; ++ks) {
                acc[i] = __builtin_amdgcn_mfma_f32_16x16x32_f16(aH[ks], bf[i][ks], acc[i], 0, 0, 0);
                acc[i] = __builtin_amdgcn_mfma_f32_16x16x32_f16(aL[ks], bf[i][ks], acc[i], 0, 0, 0);
            }
        const int rbase = tg2 * 16 + rj;
#pragma unroll
        for (int i = 0; i < 2; ++i) {
            const int c = ctl[i] * 16 + cl;
            const float bb = bt[c];
#pragma unroll
            for (int j = 0; j < 4; ++j)
                pt0[(size_t)(rbase + j) * D + c] = fmaxf(acc[i][j] + bb, 0.f);
        }
#pragma unroll
        for (int p = 0; p < 2; ++p) {
            const int c = (ctl[2 + p] - 8) * 16 + cl;
            const float bS = bs[c], bN = bh[c];
#pragma unroll
            for (int j = 0; j < 4; ++j) {
                float vS = fmaxf(acc[2 + p][j] + bS, 0.f);
                float vN = fmaxf(acc[4 + p][j] + bN, 0.f);
                psn2[(size_t)(rbase + j) * 128 + c] = __floats2half2_rn(vS, vN);
            }
        }
    }
}

// ================= gather core: one node per 32-lane half-wave =================
// psn pair layout: psn[2c]=ps[c], psn[2c+1]=pn[c]; lane owns cols 4*l32..+3 (16 B).
// 8-deep load pipeline: two 4-batches in flight ahead of the PROC batch.
#define LDV(kk) (*(const uint4*)(psn + (size_t)__shfl(sv, hbase + (kk)) * 256 + 8 * l32))

#define PROC(v, kk) {                                                     \
    const float2 p0 = __half22float2(*(const __half2*)&(v).x);            \
    const float2 p1 = __half22float2(*(const __half2*)&(v).y);            \
    const float2 p2 = __half22float2(*(const __half2*)&(v).z);            \
    const float2 p3 = __half22float2(*(const __half2*)&(v).w);            \
    float d_ = ptv.x * p0.x + ptv.y * p1.x + ptv.z * p2.x + ptv.w * p3.x; \
    d_ += __shfl_xor(d_, 1);                                              \
    d_ += __shfl_xor(d_, 2);                                              \
    const float ex_ = (base + (kk) < len) ? __expf(d_) : 0.f;             \
    sA += ex_; M0 += ex_ * p0.y; M1 += ex_ * p1.y;                        \
    M2 += ex_ * p2.y; M3 += ex_ * p3.y; }

__device__ __forceinline__ void gat_node(
        const float* __restrict__ pt, const __half* __restrict__ psn,
        const int* __restrict__ cnt, const int* __restrict__ slots,
        const float* __restrict__ Wo, const float* __restrict__ bo,
        int node, int l32, int hbase, float hv[4]) {
    const float4 ptv = *(const float4*)(pt + (size_t)node * D + 4 * l32);
    const int len = min(cnt[node], MAXDEG);          // >= 1 (self-loop)
    const int maxlen = max(len, __shfl_xor(len, 32));
    const int e0 = node * MAXDEG;

    float sA = 0.f, M0 = 0.f, M1 = 0.f, M2 = 0.f, M3 = 0.f;
    for (int base = 0; base < maxlen; base += 32) {
        const int sv = slots[e0 + min(base + l32, len - 1)];
        const int kmax = min(32, maxlen - base);
        // prologue: 8 loads in flight (clamped dup indices are L1-hot)
        uint4 v0 = LDV(0);
        uint4 v1 = LDV(min(1, kmax - 1));
        uint4 v2 = LDV(min(2, kmax - 1));
        uint4 v3 = LDV(min(3, kmax - 1));
        uint4 u0 = LDV(min(4, kmax - 1));
        uint4 u1 = LDV(min(5, kmax - 1));
        uint4 u2 = LDV(min(6, kmax - 1));
        uint4 u3 = LDV(min(7, kmax - 1));
        for (int k = 0; k < kmax; k += 4) {
            const int kn = k + 8;
            uint4 w0 = LDV(min(kn,     kmax - 1));
            uint4 w1 = LDV(min(kn + 1, kmax - 1));
            uint4 w2 = LDV(min(kn + 2, kmax - 1));
            uint4 w3 = LDV(min(kn + 3, kmax - 1));
            PROC(v0, k); PROC(v1, k + 1); PROC(v2, k + 2); PROC(v3, k + 3);
            v0 = u0; v1 = u1; v2 = u2; v3 = u3;
            u0 = w0; u1 = w1; u2 = w2; u3 = w3;
        }
    }
    const float inv = 1.f / (sA + 1e-12f);
    float av[4] = {M0 * inv, M1 * inv, M2 * inv, M3 * inv};
#pragma unroll
    for (int j = 0; j < 4; ++j) {
        av[j] += __shfl_xor(av[j], 4);
        av[j] += __shfl_xor(av[j], 8);
        av[j] += __shfl_xor(av[j], 16);
        av[j] *= 0.125f;
    }
    float a0 = bo[l32], a1 = bo[l32 + 32], a2 = bo[l32 + 64], a3 = bo[l32 + 96];
#pragma unroll
    for (int k = 0; k < 16; ++k) {
        const float val = __shfl(av[k & 3], hbase + (k >> 2));
        a0 += val * Wo[k * D + l32];
        a1 += val * Wo[k * D + l32 + 32];
        a2 += val * Wo[k * D + l32 + 64];
        a3 += val * Wo[k * D + l32 + 96];
    }
    hv[0] = fmaxf(a0, 0.f); hv[1] = fmaxf(a1, 0.f);
    hv[2] = fmaxf(a2, 0.f); hv[3] = fmaxf(a3, 0.f);
}

// ============ attn0: GAT layer0 + fused proj3(layer1) -> pt1/psn1 ============
__global__ __launch_bounds__(512) void attn0_kernel(
        const float* __restrict__ pt0, const __half* __restrict__ psn0,
        const int* __restrict__ cnt, const int* __restrict__ slots,
        const float* __restrict__ Wo, const float* __restrict__ bo,
        const __half* __restrict__ Wc1,
        const float* __restrict__ bt, const float* __restrict__ bs,
        const float* __restrict__ bh,
        float* __restrict__ pt1, __half* __restrict__ psn1) {
    __shared__ float h2s[16][132];
    const int tid  = threadIdx.x;
    const int lane = tid & 63;
    const int l32  = lane & 31;
    const int hbase = lane & 32;
    const int nidx = tid >> 5;                    // 0..15
    const int node = blockIdx.x * 16 + nidx;

    float hv[4];
    gat_node(pt0, psn0, cnt, slots, Wo, bo, node, l32, hbase, hv);
    h2s[nidx][l32]      = hv[0];
    h2s[nidx][l32 + 32] = hv[1];
    h2s[nidx][l32 + 64] = hv[2];
    h2s[nidx][l32 + 96] = hv[3];

    const int w_ = tid >> 6;                      // 0..7
    const int cl = lane & 15, kg = (lane >> 4) * 8;
    f16x8 bT[4], bS[4], bN[4];
#pragma unroll
    for (int ks = 0; ks < 4; ++ks) {
        bT[ks] = *(const f16x8*)(Wc1 + (size_t)((w_)      * 16 + cl) * 128 + ks * 32 + kg);
        bS[ks] = *(const f16x8*)(Wc1 + (size_t)((8 + w_)  * 16 + cl) * 128 + ks * 32 + kg);
        bN[ks] = *(const f16x8*)(Wc1 + (size_t)((16 + w_) * 16 + cl) * 128 + ks * 32 + kg);
    }
    __syncthreads();

    f16x8 aH[4], aL[4];
#pragma unroll
    for (int ks = 0; ks < 4; ++ks) {
        float tmp[8];
        *(float4*)tmp       = *(const float4*)&h2s[cl][ks * 32 + kg];
        *(float4*)(tmp + 4) = *(const float4*)&h2s[cl][ks * 32 + kg + 4];
        split8(tmp, aH[ks], aL[ks]);
    }
    f32x4 accT = {0.f,0.f,0.f,0.f}, accS = {0.f,0.f,0.f,0.f}, accN = {0.f,0.f,0.f,0.f};
#pragma unroll
    for (int ks = 0; ks < 4; ++ks) {
        accT = __builtin_amdgcn_mfma_f32_16x16x32_f16(aH[ks], bT[ks], accT, 0, 0, 0);
        accT = __builtin_amdgcn_mfma_f32_16x16x32_f16(aL[ks], bT[ks], accT, 0, 0, 0);
        accS = __builtin_amdgcn_mfma_f32_16x16x32_f16(aH[ks], bS[ks], accS, 0, 0, 0);
        accS = __builtin_amdgcn_mfma_f32_16x16x32_f16(aL[ks], bS[ks], accS, 0, 0, 0);
        accN = __builtin_amdgcn_mfma_f32_16x16x32_f16(aH[ks], bN[ks], accN, 0, 0, 0);
        accN = __builtin_amdgcn_mfma_f32_16x16x32_f16(aL[ks], bN[ks], accN, 0, 0, 0);
    }
    const int rbase = blockIdx.x * 16 + (lane >> 4) * 4;
    const int c = w_ * 16 + cl;
    const float bbT = bt[c], bbS = bs[c], bbN = bh[c];
    __half2* psn2 = (__half2*)psn1;
#pragma unroll
    for (int j = 0; j < 4; ++j) {
        pt1[(size_t)(rbase + j) * D + c] = fmaxf(accT[j] + bbT, 0.f);
        float vS = fmaxf(accS[j] + bbS, 0.f);
        float vN = fmaxf(accN[j] + bbN, 0.f);
        psn2[(size_t)(rbase + j) * 128 + c] = __floats2half2_rn(vS, vN);
    }
}

// ============ attn1: GAT layer1 + output head -> out ============
__global__ __launch_bounds__(512) void attn1_kernel(
        const float* __restrict__ pt1, const __half* __restrict__ psn1,
        const int* __restrict__ cnt, const int* __restrict__ slots,
        const float* __restrict__ Wo, const float* __restrict__ bo,
        const float* __restrict__ Wout, const float* __restrict__ bout,
        float* __restrict__ outp) {
    const int tid  = threadIdx.x;
    const int lane = tid & 63;
    const int l32  = lane & 31;
    const int hbase = lane & 32;
    const int node = blockIdx.x * 16 + (tid >> 5);

    float hv[4];
    gat_node(pt1, psn1, cnt, slots, Wo, bo, node, l32, hbase, hv);

    float po[8];
#pragma unroll
    for (int o = 0; o < 8; ++o)
        po[o] = hv[0] * Wout[l32 * D_OUT + o] + hv[1] * Wout[(l32 + 32) * D_OUT + o]
              + hv[2] * Wout[(l32 + 64) * D_OUT + o] + hv[3] * Wout[(l32 + 96) * D_OUT + o];
#pragma unroll
    for (int m = 1; m < 32; m <<= 1) {
#pragma unroll
        for (int o = 0; o < 8; ++o) po[o] += __shfl_xor(po[o], m);
    }
    if (l32 == 0) {
#pragma unroll
        for (int o = 0; o < 8; ++o)
            outp[(size_t)node * D_OUT + o] = po[o] + bout[o];
    }
}

// ================= launch =================
extern "C" void kernel_launch(void* const* d_in, const int* in_sizes, int n_in,
                              void* d_out, int out_size, void* d_ws, size_t ws_size,
                              hipStream_t stream) {
    const float* x    = (const float*)d_in[0];
    const int*   ei   = (const int*)  d_in[1];
    const float* W1   = (const float*)d_in[2];
    const float* b1   = (const float*)d_in[3];
    const float* W2   = (const float*)d_in[4];
    const float* b2   = (const float*)d_in[5];
    const float* Wout = (const float*)d_in[6];
    const float* bout = (const float*)d_in[7];
    float* out = (float*)d_out;

    // workspace layout
    float*  pt0  = (float*)d_ws;                          // N*D f32
    float*  pt1  = pt0 + (size_t)N_NODES * D;             // N*D f32
    __half* psn0 = (__half*)(pt1 + (size_t)N_NODES * D);  // N*256 f16
    __half* psn1 = psn0 + (size_t)N_NODES * 256;          // N*256 f16
    __half* W1c  = psn1 + (size_t)N_NODES * 256;          // 128*32
    __half* W2c  = W1c + 128 * 32;                        // 128*128
    __half* Wc2  = W2c + 128 * 128;                       // 2*384*128
    int* cnt   = (int*)(Wc2 + 2 * 384 * 128);             // N
    int* slots = cnt + N_NODES;                           // N*MAXDEG

    prep_kernel<<<527, 256, 0, stream>>>(
        W1, W2,
        (const float*)d_in[8],  (const float*)d_in[10], (const float*)d_in[12],
        (const float*)d_in[16], (const float*)d_in[18], (const float*)d_in[20],
        W1c, W2c, Wc2, cnt);

    build_fwd<<<MLP_BLOCKS + BUCKET_BLOCKS, 256, 0, stream>>>(
        ei, cnt, slots, x, W1c, W2c, b1, b2,
        Wc2,
        (const float*)d_in[9], (const float*)d_in[11], (const float*)d_in[13],
        pt0, psn0);

    attn0_kernel<<<NTILE, 512, 0, stream>>>(
        pt0, psn0, cnt, slots,
        (const float*)d_in[14], (const float*)d_in[15],   // Wo0, bo0
        Wc2 + 49152,
        (const float*)d_in[17], (const float*)d_in[19], (const float*)d_in[21],
        pt1, psn1);

    attn1_kernel<<<NTILE, 512, 0, stream>>>(
        pt1, psn1, cnt, slots,
        (const float*)d_in[22], (const float*)d_in[23],   // Wo1, bo1
        Wout, bout, out);
}

// Round 12
// 95.983 us; speedup vs baseline: 1.1534x; 1.0050x over previous
//
#include <hip/hip_runtime.h>
#include <hip/hip_fp16.h>

#define N_NODES 20000
#define N_EDGES 320000
#define E_TOT   (N_EDGES + N_NODES)     // self-loops appended virtually
#define D       128
#define D_OUT   8
#define MAXDEG  64
#define NTILE   (N_NODES / 16)          // 1250
#define MLP_BLOCKS 313
#define BUCKET_BLOCKS ((E_TOT + 255) / 256)   // 1329

typedef _Float16 f16x8 __attribute__((ext_vector_type(8)));
typedef float    f32x4 __attribute__((ext_vector_type(4)));

__device__ __forceinline__ void split8(const float* v, f16x8& hi, f16x8& lo) {
#pragma unroll
    for (int e = 0; e < 8; ++e) {
        _Float16 h = (_Float16)v[e];
        hi[e] = h; lo[e] = (_Float16)(v[e] - (float)h);
    }
}

// ================= prep: zero cnt + all weight transposes =================
__global__ void prep_kernel(const float* __restrict__ W1, const float* __restrict__ W2,
                            const float* __restrict__ Wt0, const float* __restrict__ Ws0,
                            const float* __restrict__ Wh0, const float* __restrict__ Wt1,
                            const float* __restrict__ Ws1, const float* __restrict__ Wh1,
                            __half* __restrict__ W1c, __half* __restrict__ W2c,
                            __half* __restrict__ Wc2, int* __restrict__ cnt) {
    const int b = blockIdx.x, tid = threadIdx.x;
    if (b < 79) {
        int i = b * 256 + tid;
        if (i < N_NODES) cnt[i] = 0;
        return;
    }
    if (b < 143) {
        int idx = (b - 79) * 256 + tid;        // 0..16383
        if (idx < 4096) {
            int c = idx >> 5, k = idx & 31;
            W1c[c * 32 + k] = __float2half(W1[k * D + c]);
        }
        int c = idx >> 7, k = idx & 127;
        W2c[c * 128 + k] = __float2half(W2[k * D + c]);
        return;
    }
    int bb = b - 143;                          // 0..383
    int l = bb / 192, r = bb % 192, m = r / 64, kp = r % 64;
    int k = kp * 2 + (tid >> 7), c = tid & 127;
    const float* W = (l == 0) ? (m == 0 ? Wt0 : m == 1 ? Ws0 : Wh0)
                              : (m == 0 ? Wt1 : m == 1 ? Ws1 : Wh1);
    Wc2[l * 49152 + (m * 128 + c) * 128 + k] = __float2half(W[(size_t)k * D + c]);
}

// ========== build_fwd: fused mlp1->mlp2->proj3(l0) (blocks 0..312) + bucket scatter ==========
__global__ __launch_bounds__(256) void build_fwd(
        const int* __restrict__ ei, int* __restrict__ cnt, int* __restrict__ slots,
        const float* __restrict__ x,
        const __half* __restrict__ W1c, const __half* __restrict__ W2c,
        const float* __restrict__ b1, const float* __restrict__ b2,
        const __half* __restrict__ Wc0,
        const float* __restrict__ bt, const float* __restrict__ bs,
        const float* __restrict__ bh,
        float* __restrict__ pt0, __half* __restrict__ psn0) {
    if (blockIdx.x >= MLP_BLOCKS) {            // ---- bucket scatter blocks ----
        int e = (blockIdx.x - MLP_BLOCKS) * 256 + threadIdx.x;
        if (e < E_TOT) {
            int src, dst;
            if (e < N_EDGES) { src = ei[e]; dst = ei[N_EDGES + e]; }
            else             { src = dst = e - N_EDGES; }
            int pos = atomicAdd(&cnt[dst], 1);
            if (pos < MAXDEG) slots[dst * MAXDEG + pos] = src;
        }
        return;
    }
    // ---- fused MLP + layer-0 projection; h tiles live in LDS as f16 hi/lo ----
    __shared__ __half hHi[4][16][136];   // 17 KB
    __shared__ __half hLo[4][16][136];   // 17 KB
    const int tb   = blockIdx.x;                   // 0..312
    const int tid  = threadIdx.x;
    const int lane = tid & 63, wv = tid >> 6;
    const int cl   = lane & 15, kg = (lane >> 4) * 8;
    const int rj   = (lane >> 4) * 4;
    const int tg   = min(tb * 4 + wv, NTILE - 1);

    // ---- stage 1: h1 = relu(x @ W1 + b1) ----
    {
        const int row = tg * 16 + cl;
        float tmp[8];
        *(float4*)tmp       = *(const float4*)(x + (size_t)row * 32 + kg);
        *(float4*)(tmp + 4) = *(const float4*)(x + (size_t)row * 32 + kg + 4);
        f16x8 aH, aL; split8(tmp, aH, aL);
        f32x4 acc[8];
#pragma unroll
        for (int ct = 0; ct < 8; ++ct) acc[ct] = (f32x4){0.f, 0.f, 0.f, 0.f};
#pragma unroll
        for (int ct = 0; ct < 8; ++ct) {
            const f16x8 bf = *(const f16x8*)(W1c + (size_t)(ct * 16 + cl) * 32 + kg);
            acc[ct] = __builtin_amdgcn_mfma_f32_16x16x32_f16(aH, bf, acc[ct], 0, 0, 0);
            acc[ct] = __builtin_amdgcn_mfma_f32_16x16x32_f16(aL, bf, acc[ct], 0, 0, 0);
        }
#pragma unroll
        for (int ct = 0; ct < 8; ++ct) {
            const float bb = b1[ct * 16 + cl];
#pragma unroll
            for (int j = 0; j < 4; ++j) {
                float v = fmaxf(acc[ct][j] + bb, 0.f);
                _Float16 h = (_Float16)v;
                ((_Float16*)&hHi[wv][rj + j][ct * 16 + cl])[0] = h;
                ((_Float16*)&hLo[wv][rj + j][ct * 16 + cl])[0] = (_Float16)(v - (float)h);
            }
        }
    }
    __syncthreads();
    // ---- stage 2: h = relu(h1 @ W2 + b2) ----
    {
        f16x8 aH[4], aL[4];
#pragma unroll
        for (int ks = 0; ks < 4; ++ks) {
            aH[ks] = *(const f16x8*)&hHi[wv][cl][ks * 32 + kg];
            aL[ks] = *(const f16x8*)&hLo[wv][cl][ks * 32 + kg];
        }
        f32x4 acc[8];
#pragma unroll
        for (int ct = 0; ct < 8; ++ct) acc[ct] = (f32x4){0.f, 0.f, 0.f, 0.f};
#pragma unroll
        for (int ks = 0; ks < 4; ++ks)
#pragma unroll
            for (int ct = 0; ct < 8; ++ct) {
                const f16x8 bf = *(const f16x8*)(W2c + (size_t)(ct * 16 + cl) * 128 + ks * 32 + kg);
                acc[ct] = __builtin_amdgcn_mfma_f32_16x16x32_f16(aH[ks], bf, acc[ct], 0, 0, 0);
                acc[ct] = __builtin_amdgcn_mfma_f32_16x16x32_f16(aL[ks], bf, acc[ct], 0, 0, 0);
            }
        __syncthreads();
#pragma unroll
        for (int ct = 0; ct < 8; ++ct) {
            const float bb = b2[ct * 16 + cl];
#pragma unroll
            for (int j = 0; j < 4; ++j) {
                float v = fmaxf(acc[ct][j] + bb, 0.f);
                _Float16 h = (_Float16)v;
                ((_Float16*)&hHi[wv][rj + j][ct * 16 + cl])[0] = h;
                ((_Float16*)&hLo[wv][rj + j][ct * 16 + cl])[0] = (_Float16)(v - (float)h);
            }
        }
    }
    __syncthreads();
    // ---- stage 3: proj3 layer0 ----
    const int ctl[6] = {2 * wv, 2 * wv + 1, 8 + 2 * wv, 9 + 2 * wv, 16 + 2 * wv, 17 + 2 * wv};
    f16x8 bf[6][4];
#pragma unroll
    for (int i = 0; i < 6; ++i)
#pragma unroll
        for (int ks = 0; ks < 4; ++ks)
            bf[i][ks] = *(const f16x8*)(Wc0 + (size_t)(ctl[i] * 16 + cl) * 128 + ks * 32 + kg);

    __half2* psn2 = (__half2*)psn0;
    for (int rt = 0; rt < 4; ++rt) {
        const int tg2 = min(tb * 4 + rt, NTILE - 1);
        f16x8 aH[4], aL[4];
#pragma unroll
        for (int ks = 0; ks < 4; ++ks) {
            aH[ks] = *(const f16x8*)&hHi[rt][cl][ks * 32 + kg];
            aL[ks] = *(const f16x8*)&hLo[rt][cl][ks * 32 + kg];
        }
        f32x4 acc[6];
#pragma unroll
        for (int i = 0; i < 6; ++i) acc[i] = (f32x4){0.f, 0.f, 0.f, 0.f};
#pragma unroll
        for (int i = 0; i < 6; ++i)
#pragma unroll
            for (int ks = 0; ks < 4; ++ks) {
                acc[i] = __builtin_amdgcn_mfma_f32_16x16x32_f16(aH[ks], bf[i][ks], acc[i], 0, 0, 0);
                acc[i] = __builtin_amdgcn_mfma_f32_16x16x32_f16(aL[ks], bf[i][ks], acc[i], 0, 0, 0);
            }
        const int rbase = tg2 * 16 + rj;
#pragma unroll
        for (int i = 0; i < 2; ++i) {
            const int c = ctl[i] * 16 + cl;
            const float bb = bt[c];
#pragma unroll
            for (int j = 0; j < 4; ++j)
                pt0[(size_t)(rbase + j) * D + c] = fmaxf(acc[i][j] + bb, 0.f);
        }
#pragma unroll
        for (int p = 0; p < 2; ++p) {
            const int c = (ctl[2 + p] - 8) * 16 + cl;
            const float bS = bs[c], bN = bh[c];
#pragma unroll
            for (int j = 0; j < 4; ++j) {
                float vS = fmaxf(acc[2 + p][j] + bS, 0.f);
                float vN = fmaxf(acc[4 + p][j] + bN, 0.f);
                psn2[(size_t)(rbase + j) * 128 + c] = __floats2half2_rn(vS, vN);
            }
        }
    }
}

// ================= gather core: one node per 32-lane half-wave (R8 4-deep pipeline) =================
#define LDV(kk) (*(const uint4*)(psn + (size_t)__shfl(sv, hbase + (kk)) * 256 + 8 * l32))

#define PROC(v, kk) {                                                     \
    const float2 p0 = __half22float2(*(const __half2*)&(v).x);            \
    const float2 p1 = __half22float2(*(const __half2*)&(v).y);            \
    const float2 p2 = __half22float2(*(const __half2*)&(v).z);            \
    const float2 p3 = __half22float2(*(const __half2*)&(v).w);            \
    float d_ = ptv.x * p0.x + ptv.y * p1.x + ptv.z * p2.x + ptv.w * p3.x; \
    d_ += __shfl_xor(d_, 1);                                              \
    d_ += __shfl_xor(d_, 2);                                              \
    const float ex_ = (base + (kk) < len) ? __expf(d_) : 0.f;             \
    sA += ex_; M0 += ex_ * p0.y; M1 += ex_ * p1.y;                        \
    M2 += ex_ * p2.y; M3 += ex_ * p3.y; }

__device__ __forceinline__ void gat_node(
        const float* __restrict__ pt, const __half* __restrict__ psn,
        const int* __restrict__ cnt, const int* __restrict__ slots,
        const float* __restrict__ Wo, const float* __restrict__ bo,
        int node, int l32, int hbase, float hv[4]) {
    const float4 ptv = *(const float4*)(pt + (size_t)node * D + 4 * l32);
    const int len = min(cnt[node], MAXDEG);          // >= 1 (self-loop)
    const int maxlen = max(len, __shfl_xor(len, 32));
    const int e0 = node * MAXDEG;

    float sA = 0.f, M0 = 0.f, M1 = 0.f, M2 = 0.f, M3 = 0.f;
    for (int base = 0; base < maxlen; base += 32) {
        const int sv = slots[e0 + min(base + l32, len - 1)];
        const int kmax = min(32, maxlen - base);
        uint4 va = LDV(0);
        uint4 vb = LDV(min(1, kmax - 1));
        uint4 vc = LDV(min(2, kmax - 1));
        uint4 vd = LDV(min(3, kmax - 1));
        for (int k = 0; k < kmax; k += 4) {
            const int kn = k + 4;
            uint4 wa = LDV(min(kn,     kmax - 1));
            uint4 wb = LDV(min(kn + 1, kmax - 1));
            uint4 wc = LDV(min(kn + 2, kmax - 1));
            uint4 wd = LDV(min(kn + 3, kmax - 1));
            PROC(va, k); PROC(vb, k + 1); PROC(vc, k + 2); PROC(vd, k + 3);
            va = wa; vb = wb; vc = wc; vd = wd;
        }
    }
    const float inv = 1.f / (sA + 1e-12f);
    float av[4] = {M0 * inv, M1 * inv, M2 * inv, M3 * inv};
#pragma unroll
    for (int j = 0; j < 4; ++j) {
        av[j] += __shfl_xor(av[j], 4);
        av[j] += __shfl_xor(av[j], 8);
        av[j] += __shfl_xor(av[j], 16);
        av[j] *= 0.125f;
    }
    float a0 = bo[l32], a1 = bo[l32 + 32], a2 = bo[l32 + 64], a3 = bo[l32 + 96];
#pragma unroll
    for (int k = 0; k < 16; ++k) {
        const float val = __shfl(av[k & 3], hbase + (k >> 2));
        a0 += val * Wo[k * D + l32];
        a1 += val * Wo[k * D + l32 + 32];
        a2 += val * Wo[k * D + l32 + 64];
        a3 += val * Wo[k * D + l32 + 96];
    }
    hv[0] = fmaxf(a0, 0.f); hv[1] = fmaxf(a1, 0.f);
    hv[2] = fmaxf(a2, 0.f); hv[3] = fmaxf(a3, 0.f);
}

// ============ attn0: GAT layer0 + fused proj3(layer1) -> pt1/psn1 ============
__global__ __launch_bounds__(512) void attn0_kernel(
        const float* __restrict__ pt0, const __half* __restrict__ psn0,
        const int* __restrict__ cnt, const int* __restrict__ slots,
        const float* __restrict__ Wo, const float* __restrict__ bo,
        const __half* __restrict__ Wc1,
        const float* __restrict__ bt, const float* __restrict__ bs,
        const float* __restrict__ bh,
        float* __restrict__ pt1, __half* __restrict__ psn1) {
    __shared__ float h2s[16][132];
    const int tid  = threadIdx.x;
    const int lane = tid & 63;
    const int l32  = lane & 31;
    const int hbase = lane & 32;
    const int nidx = tid >> 5;                    // 0..15
    const int node = blockIdx.x * 16 + nidx;

    float hv[4];
    gat_node(pt0, psn0, cnt, slots, Wo, bo, node, l32, hbase, hv);
    h2s[nidx][l32]      = hv[0];
    h2s[nidx][l32 + 32] = hv[1];
    h2s[nidx][l32 + 64] = hv[2];
    h2s[nidx][l32 + 96] = hv[3];

    const int w_ = tid >> 6;                      // 0..7
    const int cl = lane & 15, kg = (lane >> 4) * 8;
    f16x8 bT[4], bS[4], bN[4];
#pragma unroll
    for (int ks = 0; ks < 4; ++ks) {
        bT[ks] = *(const f16x8*)(Wc1 + (size_t)((w_)      * 16 + cl) * 128 + ks * 32 + kg);
        bS[ks] = *(const f16x8*)(Wc1 + (size_t)((8 + w_)  * 16 + cl) * 128 + ks * 32 + kg);
        bN[ks] = *(const f16x8*)(Wc1 + (size_t)((16 + w_) * 16 + cl) * 128 + ks * 32 + kg);
    }
    __syncthreads();

    f16x8 aH[4], aL[4];
#pragma unroll
    for (int ks = 0; ks < 4; ++ks) {
        float tmp[8];
        *(float4*)tmp       = *(const float4*)&h2s[cl][ks * 32 + kg];
        *(float4*)(tmp + 4) = *(const float4*)&h2s[cl][ks * 32 + kg + 4];
        split8(tmp, aH[ks], aL[ks]);
    }
    f32x4 accT = {0.f,0.f,0.f,0.f}, accS = {0.f,0.f,0.f,0.f}, accN = {0.f,0.f,0.f,0.f};
#pragma unroll
    for (int ks = 0; ks < 4; ++ks) {
        accT = __builtin_amdgcn_mfma_f32_16x16x32_f16(aH[ks], bT[ks], accT, 0, 0, 0);
        accT = __builtin_amdgcn_mfma_f32_16x16x32_f16(aL[ks], bT[ks], accT, 0, 0, 0);
        accS = __builtin_amdgcn_mfma_f32_16x16x32_f16(aH[ks], bS[ks], accS, 0, 0, 0);
        accS = __builtin_amdgcn_mfma_f32_16x16x32_f16(aL[ks], bS[ks], accS, 0, 0, 0);
        accN = __builtin_amdgcn_mfma_f32_16x16x32_f16(aH[ks], bN[ks], accN, 0, 0, 0);
        accN = __builtin_amdgcn_mfma_f32_16x16x32_f16(aL[ks], bN[ks], accN, 0, 0, 0);
    }
    const int rbase = blockIdx.x * 16 + (lane >> 4) * 4;
    const int c = w_ * 16 + cl;
    const float bbT = bt[c], bbS = bs[c], bbN = bh[c];
    __half2* psn2 = (__half2*)psn1;
#pragma unroll
    for (int j = 0; j < 4; ++j) {
        pt1[(size_t)(rbase + j) * D + c] = fmaxf(accT[j] + bbT, 0.f);
        float vS = fmaxf(accS[j] + bbS, 0.f);
        float vN = fmaxf(accN[j] + bbN, 0.f);
        psn2[(size_t)(rbase + j) * 128 + c] = __floats2half2_rn(vS, vN);
    }
}

// ============ attn1: GAT layer1 + output head -> out (256 thr = 8 nodes/block) ============
__global__ __launch_bounds__(256) void attn1_kernel(
        const float* __restrict__ pt1, const __half* __restrict__ psn1,
        const int* __restrict__ cnt, const int* __restrict__ slots,
        const float* __restrict__ Wo, const float* __restrict__ bo,
        const float* __restrict__ Wout, const float* __restrict__ bout,
        float* __restrict__ outp) {
    const int tid  = threadIdx.x;
    const int lane = tid & 63;
    const int l32  = lane & 31;
    const int hbase = lane & 32;
    const int node = blockIdx.x * 8 + (tid >> 5);

    float hv[4];
    gat_node(pt1, psn1, cnt, slots, Wo, bo, node, l32, hbase, hv);

    float po[8];
#pragma unroll
    for (int o = 0; o < 8; ++o)
        po[o] = hv[0] * Wout[l32 * D_OUT + o] + hv[1] * Wout[(l32 + 32) * D_OUT + o]
              + hv[2] * Wout[(l32 + 64) * D_OUT + o] + hv[3] * Wout[(l32 + 96) * D_OUT + o];
#pragma unroll
    for (int m = 1; m < 32; m <<= 1) {
#pragma unroll
        for (int o = 0; o < 8; ++o) po[o] += __shfl_xor(po[o], m);
    }
    if (l32 == 0) {
#pragma unroll
        for (int o = 0; o < 8; ++o)
            outp[(size_t)node * D_OUT + o] = po[o] + bout[o];
    }
}

// ================= launch =================
extern "C" void kernel_launch(void* const* d_in, const int* in_sizes, int n_in,
                              void* d_out, int out_size, void* d_ws, size_t ws_size,
                              hipStream_t stream) {
    const float* x    = (const float*)d_in[0];
    const int*   ei   = (const int*)  d_in[1];
    const float* W1   = (const float*)d_in[2];
    const float* b1   = (const float*)d_in[3];
    const float* W2   = (const float*)d_in[4];
    const float* b2   = (const float*)d_in[5];
    const float* Wout = (const float*)d_in[6];
    const float* bout = (const float*)d_in[7];
    float* out = (float*)d_out;

    // workspace layout
    float*  pt0  = (float*)d_ws;                          // N*D f32
    float*  pt1  = pt0 + (size_t)N_NODES * D;             // N*D f32
    __half* psn0 = (__half*)(pt1 + (size_t)N_NODES * D);  // N*256 f16
    __half* psn1 = psn0 + (size_t)N_NODES * 256;          // N*256 f16
    __half* W1c  = psn1 + (size_t)N_NODES * 256;          // 128*32
    __half* W2c  = W1c + 128 * 32;                        // 128*128
    __half* Wc2  = W2c + 128 * 128;                       // 2*384*128
    int* cnt   = (int*)(Wc2 + 2 * 384 * 128);             // N
    int* slots = cnt + N_NODES;                           // N*MAXDEG

    prep_kernel<<<527, 256, 0, stream>>>(
        W1, W2,
        (const float*)d_in[8],  (const float*)d_in[10], (const float*)d_in[12],
        (const float*)d_in[16], (const float*)d_in[18], (const float*)d_in[20],
        W1c, W2c, Wc2, cnt);

    build_fwd<<<MLP_BLOCKS + BUCKET_BLOCKS, 256, 0, stream>>>(
        ei, cnt, slots, x, W1c, W2c, b1, b2,
        Wc2,
        (const float*)d_in[9], (const float*)d_in[11], (const float*)d_in[13],
        pt0, psn0);

    attn0_kernel<<<NTILE, 512, 0, stream>>>(
        pt0, psn0, cnt, slots,
        (const float*)d_in[14], (const float*)d_in[15],   // Wo0, bo0
        Wc2 + 49152,
        (const float*)d_in[17], (const float*)d_in[19], (const float*)d_in[21],
        pt1, psn1);

    attn1_kernel<<<N_NODES / 8, 256, 0, stream>>>(
        pt1, psn1, cnt, slots,
        (const float*)d_in[22], (const float*)d_in[23],   // Wo1, bo1
        Wout, bout, out);
}